// Round 11
// baseline (317.491 us; speedup 1.0000x reference)
//
#include <hip/hip_runtime.h>
#include <hip/hip_fp16.h>

#define Bb 8
#define C  64
#define Hh 128
#define Ww 128
#define HW (Hh * Ww)

typedef __attribute__((ext_vector_type(8))) short b16x8;   // raw 16B block
typedef __attribute__((ext_vector_type(4))) float f32x4;
typedef _Float16 f16x8 __attribute__((ext_vector_type(8)));
typedef __fp16 fp16x2cv __attribute__((ext_vector_type(2)));  // cvt_pkrtz ret

__device__ __forceinline__ ushort f2h(float f) {
    union { _Float16 h; ushort u; } z; z.h = (_Float16)f; return z.u;
}
__device__ __forceinline__ uint pkrtz_u(float a, float b) {
    union { fp16x2cv h; uint u; } z;
    z.h = __builtin_amdgcn_cvt_pkrtz(a, b); return z.u;
}
__device__ __forceinline__ f16x8 s2h8(b16x8 s) {
    union { b16x8 s; f16x8 h; } x; x.s = s; return x.h;
}
__device__ __forceinline__ __half2 u2hh(uint u) {
    union { uint u; __half2 h; } x; x.u = u; return x.h;
}
__device__ __forceinline__ uint hh2u(__half2 h) {
    union { uint u; __half2 h; } x; x.h = h; return x.u;
}
__device__ __forceinline__ float h2f_lo(uint u) {
    union { uint u; __half2 h; } x; x.u = u; return __low2float(x.h);
}
__device__ __forceinline__ float h2f_hi(uint u) {
    union { uint u; __half2 h; } x; x.u = u; return __high2float(x.h);
}

// ---------------------------------------------------------------------------
// NCHW fp32 -> NHWC fp16 (c innermost), transposed through LDS.
// ---------------------------------------------------------------------------
__global__ void pack_nhwc(const float* __restrict__ in, ushort* __restrict__ out) {
    __shared__ ushort t[64][65];
    const int bx = blockIdx.x;
    const int b = bx >> 8, rem = bx & 255, h = rem >> 1, w0 = (rem & 1) << 6;
    const int x = threadIdx.x, wl = x & 63, cs = x >> 6;
    const float* ip = in + (((size_t)b * 64) << 14) + (h << 7) + w0 + wl;
    #pragma unroll
    for (int i = 0; i < 16; ++i) {
        const int c = i * 4 + cs;
        t[wl][c] = f2h(ip[(size_t)c << 14]);
    }
    __syncthreads();
    ushort* op = out + ((size_t)((b * Hh + h) * Ww + w0)) * 64 + wl;
    #pragma unroll
    for (int i = 0; i < 16; ++i) {
        const int w = i * 4 + cs;
        op[(size_t)w * 64] = t[w][wl];
    }
}

// Weight pack: OIHW fp32 -> [S][OCP][32] fp16 (slice s: tap s>>1, c-half s&1).
__global__ void pack_w(const float* __restrict__ src, ushort* __restrict__ dst,
                       int OC, int OCP, int KK, int n) {
    const int idx = blockIdx.x * 256 + threadIdx.x;
    if (idx >= n) return;
    const int kk = idx & 31;
    const int oc = (idx >> 5) % OCP;
    const int s = idx / (32 * OCP);
    const int c = (s & 1) * 32 + kk;
    const int t = s >> 1;
    const float v = (oc < OC) ? src[((size_t)oc * 64 + c) * KK + t] : 0.f;
    dst[idx] = f2h(v);
}

// Depthwise weight transpose: [C][KK] -> [KK][C] fp16.
__global__ void pack_dwt(const float* __restrict__ src, ushort* __restrict__ dst, int KK) {
    const int i = blockIdx.x * 256 + threadIdx.x;
    if (i < KK * 64) {
        const int t = i >> 6, ch = i & 63;
        dst[i] = f2h(src[ch * KK + t]);
    }
}

// ---------------------------------------------------------------------------
// Offset conv as MFMA implicit GEMM (fp16), full-row tile (128 pixels/block).
// 2x2 WAVE PARTITION: wave (wo,wp) owns oc-half wo x pixel-half wp. Each
// B-fragment is read from LDS by 2 waves (not 4) -> LDS-read pipe halved;
// conv becomes MFMA-bound. A-frags from global (L1/L2-cached; the 2 px-half
// waves of a block read identical lines).
// ---------------------------------------------------------------------------
template<int K, int PAD, int DIL, int OCP, int KR>
__global__ __launch_bounds__(256, 4) void conv_mfma(
    const ushort* __restrict__ xp,
    const ushort* __restrict__ wp,
    const float* __restrict__ bias,
    ushort* __restrict__ outp) {
    constexpr int WIDTH = 128 + (K - 1) * DIL;
    constexpr int S = 2 * K * K;
    constexpr int SP = S + 2;
    constexpr int NT = OCP / 16;
    constexpr int TPW = (NT + 1) / 2;       // oc tiles per oc-half wave
    constexpr int STG = KR * WIDTH * 64;
    constexpr int EPI = 128 * SP;
    constexpr int LN = STG > EPI ? STG : EPI;
    __shared__ __align__(16) ushort lds[LN];

    const int bx = blockIdx.x;
    const int b = bx >> 7, h = bx & 127;
    const int tid = threadIdx.x, lane = tid & 63, wid = tid >> 6;
    const int l15 = lane & 15, lg = lane >> 4;
    const int wo = wid & 1, wpx = wid >> 1;     // oc-half, pixel-half
    const int pxbase = wpx << 6;                // 0 or 64

    f32x4 acc[TPW][4] = {};

    const int nph = (K + KR - 1) / KR;
    for (int ph = 0; ph < nph; ++ph) {
        const int kr0 = ph * KR;
        const int krn = (K - kr0 < KR) ? (K - kr0) : KR;
        __syncthreads();
        const int chunks = krn * WIDTH * 8;
        for (int q = tid; q < chunks; q += 256) {
            const int ki = q / (WIDTH * 8);
            const int r2 = q - ki * (WIDTH * 8);
            const int widx = r2 >> 3, csl = r2 & 7;
            const int y = h - PAD + (kr0 + ki) * DIL;
            const int w = -PAD + widx;
            uint4 v = make_uint4(0, 0, 0, 0);
            if ((unsigned)y < 128u && (unsigned)w < 128u)
                v = *(const uint4*)(xp + (((size_t)(b * 128 + y) * 128 + w) << 6) + (csl << 3));
            ((uint4*)lds)[(ki * WIDTH + widx) * 8 + (csl ^ (widx & 7))] = v;
        }
        __syncthreads();

        const int t1 = (kr0 + krn) * K;
        for (int t = kr0 * K; t < t1; ++t) {
            const int ki = t / K - kr0;
            const int kj = t - (t / K) * K;
            const int s0 = 2 * t;
            b16x8 a[2][TPW];
            #pragma unroll
            for (int i = 0; i < TPW; ++i) {
                const int ot = wo * TPW + i;
                if (ot < NT) {
                    const size_t ab = ((size_t)(ot * 16 + l15)) * 32 + lg * 8;
                    a[0][i] = *(const b16x8*)(wp + (size_t)s0 * (OCP * 32) + ab);
                    a[1][i] = *(const b16x8*)(wp + (size_t)(s0 + 1) * (OCP * 32) + ab);
                }
            }
            #pragma unroll
            for (int pt = 0; pt < 4; ++pt) {
                const int wb0 = pxbase + pt * 16 + l15 + kj * DIL;
                const int idx = (ki * WIDTH + wb0) * 8 + (lg ^ (wb0 & 7));
                const b16x8 b0 = ((const b16x8*)lds)[idx];
                const b16x8 b1 = ((const b16x8*)lds)[idx ^ 4];
                #pragma unroll
                for (int i = 0; i < TPW; ++i) {
                    if (wo * TPW + i < NT) {
                        acc[i][pt] = __builtin_amdgcn_mfma_f32_16x16x32_f16(s2h8(a[0][i]), s2h8(b0), acc[i][pt], 0, 0, 0);
                        acc[i][pt] = __builtin_amdgcn_mfma_f32_16x16x32_f16(s2h8(a[1][i]), s2h8(b1), acc[i][pt], 0, 0, 0);
                    }
                }
            }
        }
    }

    // Epilogue: acc -> LDS [128 pix][SP], then flat coalesced copy (S cols).
    __syncthreads();
    #pragma unroll
    for (int i = 0; i < TPW; ++i) {
        const int ot = wo * TPW + i;
        if (ot >= NT) continue;
        #pragma unroll
        for (int r = 0; r < 4; ++r) {
            const int oc = ot * 16 + lg * 4 + r;
            if (oc < S) {
                const float bv = bias[oc];
                #pragma unroll
                for (int pt = 0; pt < 4; ++pt)
                    lds[(pxbase + pt * 16 + l15) * SP + oc] = f2h(acc[i][pt][r] + bv);
            }
        }
    }
    __syncthreads();
    constexpr int SH = S / 2, SPH = SP / 2;
    const uint* lu = (const uint*)lds;
    uint* og = (uint*)outp + ((size_t)bx << 7) * SH;
    for (int q = tid; q < 128 * SH; q += 256) {
        const int pix = q / SH, s = q - pix * SH;
        og[q] = lu[pix * SPH + s];
    }
}

// ---------------------------------------------------------------------------
// Deformable depthwise conv, NHWC fp16. 512-thread block, 32 pixels.
// XCD-swizzled grid (img = blockIdx & 7). Tap-split halves across waves.
// (At the L1 address-throughput wall: ~76% of the 4-addr/cyc floor.)
// ---------------------------------------------------------------------------
template <int K, int PAD, int DIL>
__global__ __launch_bounds__(512) void deform6(
    const ushort* __restrict__ xp,   // [B*HW][64] fp16
    const ushort* __restrict__ off,  // [B*HW][2KK] fp16
    const ushort* __restrict__ dwt,  // [KK][64] fp16
    ushort* __restrict__ outb) {     // [B*HW][64] fp16
    constexpr int KK = K * K;
    constexpr int H0 = (KK + 1) / 2;
    constexpr int SSTB = 32 * KK * 16;           // state bytes
    __shared__ __align__(16) char smem[SSTB + KK * 128];
    uint4* sST = (uint4*)smem;
    ushort* dwl = (ushort*)(smem + SSTB);

    const int tid = threadIdx.x;
    const int img = blockIdx.x & 7;              // XCD-locality swizzle
    const int pix0 = img * HW + (blockIdx.x >> 3) * 32;

    for (int i = tid; i < KK * 32; i += 512)
        ((uint*)dwl)[i] = ((const uint*)dwt)[i];

    // --- setup phase: 32*KK tasks over 512 threads ---
    const uint* og = (const uint*)off + (size_t)pix0 * KK;
    for (int q = tid; q < 32 * KK; q += 512) {
        const int pl2 = q / KK, t2 = q - pl2 * KK;
        const int pix = pix0 + pl2;
        const int h = (pix >> 7) & 127, w = pix & 127;
        const uint od = og[q];
        const int ki = t2 / K, kj = t2 - ki * K;
        const float py = (float)(h - PAD + ki * DIL) + h2f_lo(od);
        const float px = (float)(w - PAD + kj * DIL) + h2f_hi(od);
        const float y0f = floorf(py), x0f = floorf(px);
        const float wy = py - y0f, wx = px - x0f;
        const int y0 = (int)y0f, x0 = (int)x0f;
        const int y1 = y0 + 1, x1 = x0 + 1;
        const float m00 = ((unsigned)y0 < 128u && (unsigned)x0 < 128u) ? 1.f : 0.f;
        const float m01 = ((unsigned)y0 < 128u && (unsigned)x1 < 128u) ? 1.f : 0.f;
        const float m10 = ((unsigned)y1 < 128u && (unsigned)x0 < 128u) ? 1.f : 0.f;
        const float m11 = ((unsigned)y1 < 128u && (unsigned)x1 < 128u) ? 1.f : 0.f;
        const int y0c = min(max(y0, 0), 127), y1c = min(max(y1, 0), 127);
        const int x0c = min(max(x0, 0), 127), x1c = min(max(x1, 0), 127);
        const float w00 = (1.f - wy) * (1.f - wx) * m00;
        const float w01 = (1.f - wy) * wx * m01;
        const float w10 = wy * (1.f - wx) * m10;
        const float w11 = wy * wx * m11;
        const uint o00b = (uint)(((y0c << 7) | x0c) << 7);   // byte offset
        const uint o11b = (uint)(((y1c << 7) | x1c) << 7);
        const uint dxf = (uint)(x1c - x0c) << 24;            // 0 or 1<<24
        sST[q] = make_uint4(o00b | dxf, o11b,
                            pkrtz_u(w00, w01), pkrtz_u(w10, w11));
    }
    __syncthreads();

    // --- main phase ---
    const int g = tid & 7, pl = (tid >> 3) & 31, half = tid >> 8;
    const int pix = pix0 + pl;
    const int gb2 = g << 4;            // byte offset of channel group
    const char* xb8 = (const char*)xp + ((size_t)img << 21);
    const int base = pl * KK;

    __half2 acc_h[4] = {};

#define TAP(tt)                                                              \
    {                                                                        \
        const uint4 st = sST[base + (tt)];                                   \
        const uint a = st.x;                                                 \
        const uint o00 = (a & 0x00FFFFFFu) + gb2;                            \
        const uint dxb = (a >> 17) & 128u;                                   \
        const uint o11 = st.y + gb2;                                         \
        const __half2 wv0 = u2hh(st.z), wv1 = u2hh(st.w);                    \
        const __half2 w00b = __low2half2(wv0), w01b = __high2half2(wv0);     \
        const __half2 w10b = __low2half2(wv1), w11b = __high2half2(wv1);     \
        const uint4 qa = *(const uint4*)(xb8 + o00);                         \
        const uint4 qb = *(const uint4*)(xb8 + (o00 + dxb));                 \
        const uint4 qc = *(const uint4*)(xb8 + (o11 - dxb));                 \
        const uint4 qd = *(const uint4*)(xb8 + o11);                         \
        const uint4 dwv = *(const uint4*)(dwl + ((tt) << 6) + (g << 3));     \
        const uint* Ap = (const uint*)&qa;                                   \
        const uint* Bp = (const uint*)&qb;                                   \
        const uint* Cp = (const uint*)&qc;                                   \
        const uint* Dp = (const uint*)&qd;                                   \
        const uint* Wp = (const uint*)&dwv;                                  \
        _Pragma("unroll")                                                    \
        for (int j = 0; j < 4; ++j) {                                        \
            __half2 v = __hmul2(u2hh(Ap[j]), w00b);                          \
            v = __hfma2(u2hh(Bp[j]), w01b, v);                               \
            v = __hfma2(u2hh(Cp[j]), w10b, v);                               \
            v = __hfma2(u2hh(Dp[j]), w11b, v);                               \
            acc_h[j] = __hfma2(v, u2hh(Wp[j]), acc_h[j]);                    \
        }                                                                    \
    }

    if (!half) {
        #pragma unroll 2
        for (int tt = 0; tt < H0; ++tt) TAP(tt);
    } else {
        #pragma unroll 2
        for (int tt = H0; tt < KK; ++tt) TAP(tt);
    }
#undef TAP

    // --- merge halves through LDS (aliased over sST; all reads are done) ---
    __syncthreads();
    uint4* red = (uint4*)smem;
    if (half) {
        red[tid & 255] = make_uint4(hh2u(acc_h[0]), hh2u(acc_h[1]),
                                    hh2u(acc_h[2]), hh2u(acc_h[3]));
    }
    __syncthreads();
    if (!half) {
        const uint4 o = red[tid];
        acc_h[0] = __hadd2(acc_h[0], u2hh(o.x));
        acc_h[1] = __hadd2(acc_h[1], u2hh(o.y));
        acc_h[2] = __hadd2(acc_h[2], u2hh(o.z));
        acc_h[3] = __hadd2(acc_h[3], u2hh(o.w));
        uint o4[4];
        #pragma unroll
        for (int j = 0; j < 4; ++j) o4[j] = hh2u(acc_h[j]);
        *(uint4*)(outb + ((size_t)pix << 6) + (g << 3)) = *(uint4*)o4;
    }
}

// ---------------------------------------------------------------------------
// Fused 1x1 conv (fp16 MFMA) + bias + u*attn. attn NHWC fp16; x/out NCHW f32.
// ---------------------------------------------------------------------------
__global__ __launch_bounds__(256) void pw_mfma(
    const ushort* __restrict__ attn, const ushort* __restrict__ wp2,
    const float* __restrict__ b1, const float* __restrict__ x,
    float* __restrict__ out) {
    __shared__ __align__(16) ushort lds[64 * 64];
    const int tid = threadIdx.x, lane = tid & 63, wid = tid >> 6;
    const int l15 = lane & 15, lg = lane >> 4;
    const int pix0 = blockIdx.x << 6;

    const uint4* src = (const uint4*)(attn + ((size_t)pix0 << 6));
    for (int q = tid; q < 512; q += 256) {
        const int widx = q >> 3, csl = q & 7;
        ((uint4*)lds)[widx * 8 + (csl ^ (widx & 7))] = src[q];
    }
    __syncthreads();

    const b16x8 a0 = *(const b16x8*)(wp2 + ((size_t)(wid * 16 + l15)) * 32 + lg * 8);
    const b16x8 a1 = *(const b16x8*)(wp2 + ((size_t)(64 + wid * 16 + l15)) * 32 + lg * 8);
    f32x4 acc[4] = {};
    #pragma unroll
    for (int pt = 0; pt < 4; ++pt) {
        const int wb = pt * 16 + l15;
        const int idx = wb * 8 + (lg ^ (wb & 7));
        const b16x8 b0 = ((const b16x8*)lds)[idx];
        const b16x8 b1v = ((const b16x8*)lds)[idx ^ 4];
        acc[pt] = __builtin_amdgcn_mfma_f32_16x16x32_f16(s2h8(a0), s2h8(b0), acc[pt], 0, 0, 0);
        acc[pt] = __builtin_amdgcn_mfma_f32_16x16x32_f16(s2h8(a1), s2h8(b1v), acc[pt], 0, 0, 0);
    }

    const int b = pix0 >> 14, hw0 = pix0 & 16383;
    #pragma unroll
    for (int r = 0; r < 4; ++r) {
        const int oc = wid * 16 + lg * 4 + r;
        const float bv = b1[oc];
        const size_t base = (((size_t)b * 64 + oc) << 14) + hw0;
        #pragma unroll
        for (int pt = 0; pt < 4; ++pt) {
            const size_t oi = base + pt * 16 + l15;
            out[oi] = x[oi] * (acc[pt][r] + bv);
        }
    }
}

extern "C" void kernel_launch(void* const* d_in, const int* in_sizes, int n_in,
                              void* d_out, int out_size, void* d_ws, size_t ws_size,
                              hipStream_t stream) {
    const float* x       = (const float*)d_in[0];
    const float* off0_w  = (const float*)d_in[1];
    const float* off0_b  = (const float*)d_in[2];
    const float* dw0_w   = (const float*)d_in[3];
    const float* off1_w  = (const float*)d_in[4];
    const float* off1_b  = (const float*)d_in[5];
    const float* dw1_w   = (const float*)d_in[6];
    const float* conv1_w = (const float*)d_in[7];
    const float* conv1_b = (const float*)d_in[8];
    float* out = (float*)d_out;

    const size_t NPX = (size_t)Bb * HW;
    ushort* xp     = (ushort*)d_ws;
    ushort* attn0b = xp + NPX * 64;
    ushort* attn1b = attn0b + NPX * 64;
    ushort* offb   = attn1b + NPX * 64;
    ushort* wp0    = offb + NPX * 98;
    ushort* wp1    = wp0 + 50 * 64 * 32;
    ushort* wpP    = wp1 + 98 * 112 * 32;
    ushort* dwt0   = wpP + 2 * 64 * 32;
    ushort* dwt1   = dwt0 + 25 * 64;

    const dim3 blk(256);

    pack_nhwc<<<2048, blk, 0, stream>>>(x, xp);
    pack_w<<<(50 * 64 * 32 + 255) / 256, blk, 0, stream>>>(off0_w, wp0, 50, 64, 25, 50 * 64 * 32);
    pack_w<<<(98 * 112 * 32 + 255) / 256, blk, 0, stream>>>(off1_w, wp1, 98, 112, 49, 98 * 112 * 32);
    pack_w<<<16, blk, 0, stream>>>(conv1_w, wpP, 64, 64, 1, 2 * 64 * 32);
    pack_dwt<<<(25 * 64 + 255) / 256, blk, 0, stream>>>(dw0_w, dwt0, 25);
    pack_dwt<<<(49 * 64 + 255) / 256, blk, 0, stream>>>(dw1_w, dwt1, 49);

    // Stage 1
    conv_mfma<5, 2, 1, 64, 2><<<1024, blk, 0, stream>>>(xp, wp0, off0_b, offb);
    deform6<5, 2, 1><<<4096, 512, 0, stream>>>(xp, offb, dwt0, attn0b);

    // Stage 2
    conv_mfma<7, 9, 3, 112, 2><<<1024, blk, 0, stream>>>(attn0b, wp1, off1_b, offb);
    deform6<7, 9, 3><<<4096, 512, 0, stream>>>(attn0b, offb, dwt1, attn1b);

    // Stage 3
    pw_mfma<<<2048, blk, 0, stream>>>(attn1b, wpP, conv1_b, x, out);
}

// Round 12
// 308.830 us; speedup vs baseline: 1.0280x; 1.0280x over previous
//
#include <hip/hip_runtime.h>
#include <hip/hip_fp16.h>

#define Bb 8
#define C  64
#define Hh 128
#define Ww 128
#define HW (Hh * Ww)

typedef __attribute__((ext_vector_type(8))) short b16x8;   // raw 16B block
typedef __attribute__((ext_vector_type(4))) float f32x4;
typedef _Float16 f16x8 __attribute__((ext_vector_type(8)));
typedef __fp16 fp16x2cv __attribute__((ext_vector_type(2)));  // cvt_pkrtz ret

__device__ __forceinline__ ushort f2h(float f) {
    union { _Float16 h; ushort u; } z; z.h = (_Float16)f; return z.u;
}
__device__ __forceinline__ uint pkrtz_u(float a, float b) {
    union { fp16x2cv h; uint u; } z;
    z.h = __builtin_amdgcn_cvt_pkrtz(a, b); return z.u;
}
__device__ __forceinline__ f16x8 s2h8(b16x8 s) {
    union { b16x8 s; f16x8 h; } x; x.s = s; return x.h;
}
__device__ __forceinline__ __half2 u2hh(uint u) {
    union { uint u; __half2 h; } x; x.u = u; return x.h;
}
__device__ __forceinline__ uint hh2u(__half2 h) {
    union { uint u; __half2 h; } x; x.h = h; return x.u;
}
__device__ __forceinline__ float h2f_lo(uint u) {
    union { uint u; __half2 h; } x; x.u = u; return __low2float(x.h);
}
__device__ __forceinline__ float h2f_hi(uint u) {
    union { uint u; __half2 h; } x; x.u = u; return __high2float(x.h);
}

// ---------------------------------------------------------------------------
// NCHW fp32 -> NHWC fp16 (c innermost), transposed through LDS.
// ---------------------------------------------------------------------------
__global__ void pack_nhwc(const float* __restrict__ in, ushort* __restrict__ out) {
    __shared__ ushort t[64][65];
    const int bx = blockIdx.x;
    const int b = bx >> 8, rem = bx & 255, h = rem >> 1, w0 = (rem & 1) << 6;
    const int x = threadIdx.x, wl = x & 63, cs = x >> 6;
    const float* ip = in + (((size_t)b * 64) << 14) + (h << 7) + w0 + wl;
    #pragma unroll
    for (int i = 0; i < 16; ++i) {
        const int c = i * 4 + cs;
        t[wl][c] = f2h(ip[(size_t)c << 14]);
    }
    __syncthreads();
    ushort* op = out + ((size_t)((b * Hh + h) * Ww + w0)) * 64 + wl;
    #pragma unroll
    for (int i = 0; i < 16; ++i) {
        const int w = i * 4 + cs;
        op[(size_t)w * 64] = t[w][wl];
    }
}

// Weight pack: OIHW fp32 -> [S][OCP][32] fp16 (slice s: tap s>>1, c-half s&1).
__global__ void pack_w(const float* __restrict__ src, ushort* __restrict__ dst,
                       int OC, int OCP, int KK, int n) {
    const int idx = blockIdx.x * 256 + threadIdx.x;
    if (idx >= n) return;
    const int kk = idx & 31;
    const int oc = (idx >> 5) % OCP;
    const int s = idx / (32 * OCP);
    const int c = (s & 1) * 32 + kk;
    const int t = s >> 1;
    const float v = (oc < OC) ? src[((size_t)oc * 64 + c) * KK + t] : 0.f;
    dst[idx] = f2h(v);
}

// Depthwise weight transpose: [C][KK] -> [KK][C] fp16.
__global__ void pack_dwt(const float* __restrict__ src, ushort* __restrict__ dst, int KK) {
    const int i = blockIdx.x * 256 + threadIdx.x;
    if (i < KK * 64) {
        const int t = i >> 6, ch = i & 63;
        dst[i] = f2h(src[ch * KK + t]);
    }
}

// ---------------------------------------------------------------------------
// Offset conv as MFMA implicit GEMM (fp16), full-row tile (128 pixels/block).
// R7 wave structure (each wave owns NT/4 oc-tiles x all 128 px) + 1-tap
// A-fragment software pipeline: LOADA(t+1) issues before DOTAP(t), hiding
// the ~300cy L2 latency of weight loads under a full tap of MFMA+LDS work.
// Named ping-pong sets a0/a1 (no runtime reg indexing -> no scratch).
// ---------------------------------------------------------------------------
template<int K, int PAD, int DIL, int OCP, int KR>
__global__ __launch_bounds__(256, 4) void conv_mfma(
    const ushort* __restrict__ xp,
    const ushort* __restrict__ wp,
    const float* __restrict__ bias,
    ushort* __restrict__ outp) {
    constexpr int WIDTH = 128 + (K - 1) * DIL;
    constexpr int S = 2 * K * K;
    constexpr int SP = S + 2;
    constexpr int NT = OCP / 16;
    constexpr int TPW = (NT + 3) / 4;
    constexpr int STG = KR * WIDTH * 64;
    constexpr int EPI = 128 * SP;
    constexpr int LN = STG > EPI ? STG : EPI;
    __shared__ __align__(16) ushort lds[LN];

    const int bx = blockIdx.x;
    const int b = bx >> 7, h = bx & 127;
    const int tid = threadIdx.x, lane = tid & 63, wid = tid >> 6;
    const int l15 = lane & 15, lg = lane >> 4;

    f32x4 acc[TPW][8] = {};

#define LOADA(A_, T_)                                                        \
    {                                                                        \
        const int s0_ = 2 * (T_);                                            \
        _Pragma("unroll")                                                    \
        for (int i = 0; i < TPW; ++i) {                                      \
            if (wid + 4 * i < NT) {                                          \
                const int ot = wid + 4 * i;                                  \
                const size_t ab = ((size_t)(ot * 16 + l15)) * 32 + lg * 8;   \
                A_[0][i] = *(const b16x8*)(wp + (size_t)s0_ * (OCP * 32) + ab); \
                A_[1][i] = *(const b16x8*)(wp + (size_t)(s0_ + 1) * (OCP * 32) + ab); \
            }                                                                \
        }                                                                    \
    }

#define DOTAP(A_, T_)                                                        \
    {                                                                        \
        const int tt_ = (T_);                                                \
        const int ki_ = tt_ / K - kr0;                                       \
        const int kj_ = tt_ - (tt_ / K) * K;                                 \
        const int wb0 = l15 + kj_ * DIL;                                     \
        int idx = (ki_ * WIDTH + wb0) * 8 + (lg ^ (wb0 & 7));                \
        _Pragma("unroll")                                                    \
        for (int pt = 0; pt < 8; ++pt) {                                     \
            const b16x8 b0 = ((const b16x8*)lds)[idx];                       \
            const b16x8 b1 = ((const b16x8*)lds)[idx ^ 4];                   \
            _Pragma("unroll")                                                \
            for (int i = 0; i < TPW; ++i) {                                  \
                if (wid + 4 * i < NT) {                                      \
                    acc[i][pt] = __builtin_amdgcn_mfma_f32_16x16x32_f16(s2h8(A_[0][i]), s2h8(b0), acc[i][pt], 0, 0, 0); \
                    acc[i][pt] = __builtin_amdgcn_mfma_f32_16x16x32_f16(s2h8(A_[1][i]), s2h8(b1), acc[i][pt], 0, 0, 0); \
                }                                                            \
            }                                                                \
            idx += 128;                                                      \
        }                                                                    \
    }

    const int nph = (K + KR - 1) / KR;
    for (int ph = 0; ph < nph; ++ph) {
        const int kr0 = ph * KR;
        const int krn = (K - kr0 < KR) ? (K - kr0) : KR;
        __syncthreads();
        const int chunks = krn * WIDTH * 8;
        for (int q = tid; q < chunks; q += 256) {
            const int ki = q / (WIDTH * 8);
            const int r2 = q - ki * (WIDTH * 8);
            const int widx = r2 >> 3, csl = r2 & 7;
            const int y = h - PAD + (kr0 + ki) * DIL;
            const int w = -PAD + widx;
            uint4 v = make_uint4(0, 0, 0, 0);
            if ((unsigned)y < 128u && (unsigned)w < 128u)
                v = *(const uint4*)(xp + (((size_t)(b * 128 + y) * 128 + w) << 6) + (csl << 3));
            ((uint4*)lds)[(ki * WIDTH + widx) * 8 + (csl ^ (widx & 7))] = v;
        }
        __syncthreads();

        const int t0 = kr0 * K, t1 = (kr0 + krn) * K;
        b16x8 a0[2][TPW], a1[2][TPW];
        LOADA(a0, t0);
        for (int t = t0; t < t1; t += 2) {
            if (t + 1 < t1) LOADA(a1, t + 1);
            DOTAP(a0, t);
            if (t + 2 < t1) LOADA(a0, t + 2);
            if (t + 1 < t1) DOTAP(a1, t + 1);
        }
    }
#undef LOADA
#undef DOTAP

    // Epilogue: acc -> LDS [128 pix][SP], then flat coalesced copy (S cols).
    __syncthreads();
    #pragma unroll
    for (int i = 0; i < TPW; ++i) {
        const int ot = wid + 4 * i;
        if (ot >= NT) continue;
        #pragma unroll
        for (int r = 0; r < 4; ++r) {
            const int oc = ot * 16 + lg * 4 + r;
            if (oc < S) {
                const float bv = bias[oc];
                #pragma unroll
                for (int pt = 0; pt < 8; ++pt)
                    lds[(pt * 16 + l15) * SP + oc] = f2h(acc[i][pt][r] + bv);
            }
        }
    }
    __syncthreads();
    constexpr int SH = S / 2, SPH = SP / 2;
    const uint* lu = (const uint*)lds;
    uint* og = (uint*)outp + ((size_t)bx << 7) * SH;
    for (int q = tid; q < 128 * SH; q += 256) {
        const int pix = q / SH, s = q - pix * SH;
        og[q] = lu[pix * SPH + s];
    }
}

// ---------------------------------------------------------------------------
// Deformable depthwise conv, NHWC fp16. 512-thread block, 32 pixels.
// XCD-swizzled grid (img = blockIdx & 7). Tap-split halves across waves.
// (At the L1 address-throughput wall: ~76% of the 4-addr/cyc floor.)
// ---------------------------------------------------------------------------
template <int K, int PAD, int DIL>
__global__ __launch_bounds__(512) void deform6(
    const ushort* __restrict__ xp,   // [B*HW][64] fp16
    const ushort* __restrict__ off,  // [B*HW][2KK] fp16
    const ushort* __restrict__ dwt,  // [KK][64] fp16
    ushort* __restrict__ outb) {     // [B*HW][64] fp16
    constexpr int KK = K * K;
    constexpr int H0 = (KK + 1) / 2;
    constexpr int SSTB = 32 * KK * 16;           // state bytes
    __shared__ __align__(16) char smem[SSTB + KK * 128];
    uint4* sST = (uint4*)smem;
    ushort* dwl = (ushort*)(smem + SSTB);

    const int tid = threadIdx.x;
    const int img = blockIdx.x & 7;              // XCD-locality swizzle
    const int pix0 = img * HW + (blockIdx.x >> 3) * 32;

    for (int i = tid; i < KK * 32; i += 512)
        ((uint*)dwl)[i] = ((const uint*)dwt)[i];

    // --- setup phase: 32*KK tasks over 512 threads ---
    const uint* og = (const uint*)off + (size_t)pix0 * KK;
    for (int q = tid; q < 32 * KK; q += 512) {
        const int pl2 = q / KK, t2 = q - pl2 * KK;
        const int pix = pix0 + pl2;
        const int h = (pix >> 7) & 127, w = pix & 127;
        const uint od = og[q];
        const int ki = t2 / K, kj = t2 - ki * K;
        const float py = (float)(h - PAD + ki * DIL) + h2f_lo(od);
        const float px = (float)(w - PAD + kj * DIL) + h2f_hi(od);
        const float y0f = floorf(py), x0f = floorf(px);
        const float wy = py - y0f, wx = px - x0f;
        const int y0 = (int)y0f, x0 = (int)x0f;
        const int y1 = y0 + 1, x1 = x0 + 1;
        const float m00 = ((unsigned)y0 < 128u && (unsigned)x0 < 128u) ? 1.f : 0.f;
        const float m01 = ((unsigned)y0 < 128u && (unsigned)x1 < 128u) ? 1.f : 0.f;
        const float m10 = ((unsigned)y1 < 128u && (unsigned)x0 < 128u) ? 1.f : 0.f;
        const float m11 = ((unsigned)y1 < 128u && (unsigned)x1 < 128u) ? 1.f : 0.f;
        const int y0c = min(max(y0, 0), 127), y1c = min(max(y1, 0), 127);
        const int x0c = min(max(x0, 0), 127), x1c = min(max(x1, 0), 127);
        const float w00 = (1.f - wy) * (1.f - wx) * m00;
        const float w01 = (1.f - wy) * wx * m01;
        const float w10 = wy * (1.f - wx) * m10;
        const float w11 = wy * wx * m11;
        const uint o00b = (uint)(((y0c << 7) | x0c) << 7);   // byte offset
        const uint o11b = (uint)(((y1c << 7) | x1c) << 7);
        const uint dxf = (uint)(x1c - x0c) << 24;            // 0 or 1<<24
        sST[q] = make_uint4(o00b | dxf, o11b,
                            pkrtz_u(w00, w01), pkrtz_u(w10, w11));
    }
    __syncthreads();

    // --- main phase ---
    const int g = tid & 7, pl = (tid >> 3) & 31, half = tid >> 8;
    const int pix = pix0 + pl;
    const int gb2 = g << 4;            // byte offset of channel group
    const char* xb8 = (const char*)xp + ((size_t)img << 21);
    const int base = pl * KK;

    __half2 acc_h[4] = {};

#define TAP(tt)                                                              \
    {                                                                        \
        const uint4 st = sST[base + (tt)];                                   \
        const uint a = st.x;                                                 \
        const uint o00 = (a & 0x00FFFFFFu) + gb2;                            \
        const uint dxb = (a >> 17) & 128u;                                   \
        const uint o11 = st.y + gb2;                                         \
        const __half2 wv0 = u2hh(st.z), wv1 = u2hh(st.w);                    \
        const __half2 w00b = __low2half2(wv0), w01b = __high2half2(wv0);     \
        const __half2 w10b = __low2half2(wv1), w11b = __high2half2(wv1);     \
        const uint4 qa = *(const uint4*)(xb8 + o00);                         \
        const uint4 qb = *(const uint4*)(xb8 + (o00 + dxb));                 \
        const uint4 qc = *(const uint4*)(xb8 + (o11 - dxb));                 \
        const uint4 qd = *(const uint4*)(xb8 + o11);                         \
        const uint4 dwv = *(const uint4*)(dwl + ((tt) << 6) + (g << 3));     \
        const uint* Ap = (const uint*)&qa;                                   \
        const uint* Bp = (const uint*)&qb;                                   \
        const uint* Cp = (const uint*)&qc;                                   \
        const uint* Dp = (const uint*)&qd;                                   \
        const uint* Wp = (const uint*)&dwv;                                  \
        _Pragma("unroll")                                                    \
        for (int j = 0; j < 4; ++j) {                                        \
            __half2 v = __hmul2(u2hh(Ap[j]), w00b);                          \
            v = __hfma2(u2hh(Bp[j]), w01b, v);                               \
            v = __hfma2(u2hh(Cp[j]), w10b, v);                               \
            v = __hfma2(u2hh(Dp[j]), w11b, v);                               \
            acc_h[j] = __hfma2(v, u2hh(Wp[j]), acc_h[j]);                    \
        }                                                                    \
    }

    if (!half) {
        #pragma unroll 2
        for (int tt = 0; tt < H0; ++tt) TAP(tt);
    } else {
        #pragma unroll 2
        for (int tt = H0; tt < KK; ++tt) TAP(tt);
    }
#undef TAP

    // --- merge halves through LDS (aliased over sST; all reads are done) ---
    __syncthreads();
    uint4* red = (uint4*)smem;
    if (half) {
        red[tid & 255] = make_uint4(hh2u(acc_h[0]), hh2u(acc_h[1]),
                                    hh2u(acc_h[2]), hh2u(acc_h[3]));
    }
    __syncthreads();
    if (!half) {
        const uint4 o = red[tid];
        acc_h[0] = __hadd2(acc_h[0], u2hh(o.x));
        acc_h[1] = __hadd2(acc_h[1], u2hh(o.y));
        acc_h[2] = __hadd2(acc_h[2], u2hh(o.z));
        acc_h[3] = __hadd2(acc_h[3], u2hh(o.w));
        uint o4[4];
        #pragma unroll
        for (int j = 0; j < 4; ++j) o4[j] = hh2u(acc_h[j]);
        *(uint4*)(outb + ((size_t)pix << 6) + (g << 3)) = *(uint4*)o4;
    }
}

// ---------------------------------------------------------------------------
// Fused 1x1 conv (fp16 MFMA) + bias + u*attn. attn NHWC fp16; x/out NCHW f32.
// ---------------------------------------------------------------------------
__global__ __launch_bounds__(256) void pw_mfma(
    const ushort* __restrict__ attn, const ushort* __restrict__ wp2,
    const float* __restrict__ b1, const float* __restrict__ x,
    float* __restrict__ out) {
    __shared__ __align__(16) ushort lds[64 * 64];
    const int tid = threadIdx.x, lane = tid & 63, wid = tid >> 6;
    const int l15 = lane & 15, lg = lane >> 4;
    const int pix0 = blockIdx.x << 6;

    const uint4* src = (const uint4*)(attn + ((size_t)pix0 << 6));
    for (int q = tid; q < 512; q += 256) {
        const int widx = q >> 3, csl = q & 7;
        ((uint4*)lds)[widx * 8 + (csl ^ (widx & 7))] = src[q];
    }
    __syncthreads();

    const b16x8 a0 = *(const b16x8*)(wp2 + ((size_t)(wid * 16 + l15)) * 32 + lg * 8);
    const b16x8 a1 = *(const b16x8*)(wp2 + ((size_t)(64 + wid * 16 + l15)) * 32 + lg * 8);
    f32x4 acc[4] = {};
    #pragma unroll
    for (int pt = 0; pt < 4; ++pt) {
        const int wb = pt * 16 + l15;
        const int idx = wb * 8 + (lg ^ (wb & 7));
        const b16x8 b0 = ((const b16x8*)lds)[idx];
        const b16x8 b1v = ((const b16x8*)lds)[idx ^ 4];
        acc[pt] = __builtin_amdgcn_mfma_f32_16x16x32_f16(s2h8(a0), s2h8(b0), acc[pt], 0, 0, 0);
        acc[pt] = __builtin_amdgcn_mfma_f32_16x16x32_f16(s2h8(a1), s2h8(b1v), acc[pt], 0, 0, 0);
    }

    const int b = pix0 >> 14, hw0 = pix0 & 16383;
    #pragma unroll
    for (int r = 0; r < 4; ++r) {
        const int oc = wid * 16 + lg * 4 + r;
        const float bv = b1[oc];
        const size_t base = (((size_t)b * 64 + oc) << 14) + hw0;
        #pragma unroll
        for (int pt = 0; pt < 4; ++pt) {
            const size_t oi = base + pt * 16 + l15;
            out[oi] = x[oi] * (acc[pt][r] + bv);
        }
    }
}

extern "C" void kernel_launch(void* const* d_in, const int* in_sizes, int n_in,
                              void* d_out, int out_size, void* d_ws, size_t ws_size,
                              hipStream_t stream) {
    const float* x       = (const float*)d_in[0];
    const float* off0_w  = (const float*)d_in[1];
    const float* off0_b  = (const float*)d_in[2];
    const float* dw0_w   = (const float*)d_in[3];
    const float* off1_w  = (const float*)d_in[4];
    const float* off1_b  = (const float*)d_in[5];
    const float* dw1_w   = (const float*)d_in[6];
    const float* conv1_w = (const float*)d_in[7];
    const float* conv1_b = (const float*)d_in[8];
    float* out = (float*)d_out;

    const size_t NPX = (size_t)Bb * HW;
    ushort* xp     = (ushort*)d_ws;
    ushort* attn0b = xp + NPX * 64;
    ushort* attn1b = attn0b + NPX * 64;
    ushort* offb   = attn1b + NPX * 64;
    ushort* wp0    = offb + NPX * 98;
    ushort* wp1    = wp0 + 50 * 64 * 32;
    ushort* wpP    = wp1 + 98 * 112 * 32;
    ushort* dwt0   = wpP + 2 * 64 * 32;
    ushort* dwt1   = dwt0 + 25 * 64;

    const dim3 blk(256);

    pack_nhwc<<<2048, blk, 0, stream>>>(x, xp);
    pack_w<<<(50 * 64 * 32 + 255) / 256, blk, 0, stream>>>(off0_w, wp0, 50, 64, 25, 50 * 64 * 32);
    pack_w<<<(98 * 112 * 32 + 255) / 256, blk, 0, stream>>>(off1_w, wp1, 98, 112, 49, 98 * 112 * 32);
    pack_w<<<16, blk, 0, stream>>>(conv1_w, wpP, 64, 64, 1, 2 * 64 * 32);
    pack_dwt<<<(25 * 64 + 255) / 256, blk, 0, stream>>>(dw0_w, dwt0, 25);
    pack_dwt<<<(49 * 64 + 255) / 256, blk, 0, stream>>>(dw1_w, dwt1, 49);

    // Stage 1
    conv_mfma<5, 2, 1, 64, 2><<<1024, blk, 0, stream>>>(xp, wp0, off0_b, offb);
    deform6<5, 2, 1><<<4096, 512, 0, stream>>>(xp, offb, dwt0, attn0b);

    // Stage 2
    conv_mfma<7, 9, 3, 112, 2><<<1024, blk, 0, stream>>>(attn0b, wp1, off1_b, offb);
    deform6<7, 9, 3><<<4096, 512, 0, stream>>>(attn0b, offb, dwt1, attn1b);

    // Stage 3
    pw_mfma<<<2048, blk, 0, stream>>>(attn1b, wpP, conv1_b, x, out);
}

// Round 13
// 302.182 us; speedup vs baseline: 1.0507x; 1.0220x over previous
//
#include <hip/hip_runtime.h>
#include <hip/hip_fp16.h>

#define Bb 8
#define C  64
#define Hh 128
#define Ww 128
#define HW (Hh * Ww)

typedef __attribute__((ext_vector_type(8))) short b16x8;   // raw 16B block
typedef __attribute__((ext_vector_type(4))) float f32x4;
typedef _Float16 f16x8 __attribute__((ext_vector_type(8)));
typedef __fp16 fp16x2cv __attribute__((ext_vector_type(2)));  // cvt_pkrtz ret

__device__ __forceinline__ ushort f2h(float f) {
    union { _Float16 h; ushort u; } z; z.h = (_Float16)f; return z.u;
}
__device__ __forceinline__ uint pkrtz_u(float a, float b) {
    union { fp16x2cv h; uint u; } z;
    z.h = __builtin_amdgcn_cvt_pkrtz(a, b); return z.u;
}
__device__ __forceinline__ f16x8 s2h8(b16x8 s) {
    union { b16x8 s; f16x8 h; } x; x.s = s; return x.h;
}
__device__ __forceinline__ __half2 u2hh(uint u) {
    union { uint u; __half2 h; } x; x.u = u; return x.h;
}
__device__ __forceinline__ uint hh2u(__half2 h) {
    union { uint u; __half2 h; } x; x.h = h; return x.u;
}
__device__ __forceinline__ float h2f_lo(uint u) {
    union { uint u; __half2 h; } x; x.u = u; return __low2float(x.h);
}
__device__ __forceinline__ float h2f_hi(uint u) {
    union { uint u; __half2 h; } x; x.u = u; return __high2float(x.h);
}

// ---------------------------------------------------------------------------
// NCHW fp32 -> NHWC fp16 (c innermost), transposed through LDS.
// ---------------------------------------------------------------------------
__global__ void pack_nhwc(const float* __restrict__ in, ushort* __restrict__ out) {
    __shared__ ushort t[64][65];
    const int bx = blockIdx.x;
    const int b = bx >> 8, rem = bx & 255, h = rem >> 1, w0 = (rem & 1) << 6;
    const int x = threadIdx.x, wl = x & 63, cs = x >> 6;
    const float* ip = in + (((size_t)b * 64) << 14) + (h << 7) + w0 + wl;
    #pragma unroll
    for (int i = 0; i < 16; ++i) {
        const int c = i * 4 + cs;
        t[wl][c] = f2h(ip[(size_t)c << 14]);
    }
    __syncthreads();
    ushort* op = out + ((size_t)((b * Hh + h) * Ww + w0)) * 64 + wl;
    #pragma unroll
    for (int i = 0; i < 16; ++i) {
        const int w = i * 4 + cs;
        op[(size_t)w * 64] = t[w][wl];
    }
}

// ---------------------------------------------------------------------------
// ONE fused weight-pack kernel (5 jobs): 3x pack_w + 2x pack_dwt.
// pack_w: OIHW fp32 -> [S][OCP][32] fp16; pack_dwt: [C][KK] -> [KK][C] fp16.
// ---------------------------------------------------------------------------
__device__ __forceinline__ void do_pack_w(const float* src, ushort* dst,
                                          int OC, int OCP, int KK, int idx) {
    const int kk = idx & 31;
    const int oc = (idx >> 5) % OCP;
    const int s = idx / (32 * OCP);
    const int c = (s & 1) * 32 + kk;
    const int t = s >> 1;
    const float v = (oc < OC) ? src[((size_t)oc * 64 + c) * KK + t] : 0.f;
    dst[idx] = f2h(v);
}
__global__ void pack_all(const float* __restrict__ off0_w, ushort* __restrict__ wp0,
                         const float* __restrict__ off1_w, ushort* __restrict__ wp1,
                         const float* __restrict__ conv1_w, ushort* __restrict__ wpP,
                         const float* __restrict__ dw0_w, ushort* __restrict__ dwt0,
                         const float* __restrict__ dw1_w, ushort* __restrict__ dwt1) {
    const int N0 = 50 * 2 * 64 * 32;       // 204800? no: 2*25 slices*... = 102400
    // job sizes
    const int n0 = 2 * 25 * 64 * 32;       // 102400
    const int n1 = 2 * 49 * 112 * 32;      // 351232
    const int n2 = 2 * 64 * 32;            // 4096
    const int n3 = 25 * 64;                // 1600
    const int n4 = 49 * 64;                // 3136
    (void)N0;
    int idx = blockIdx.x * 256 + threadIdx.x;
    if (idx < n0) { do_pack_w(off0_w, wp0, 50, 64, 25, idx); return; }
    idx -= n0;
    if (idx < n1) { do_pack_w(off1_w, wp1, 98, 112, 49, idx); return; }
    idx -= n1;
    if (idx < n2) { do_pack_w(conv1_w, wpP, 64, 64, 1, idx); return; }
    idx -= n2;
    if (idx < n3) { const int t = idx >> 6, ch = idx & 63;
                    dwt0[idx] = f2h(dw0_w[ch * 25 + t]); return; }
    idx -= n3;
    if (idx < n4) { const int t = idx >> 6, ch = idx & 63;
                    dwt1[idx] = f2h(dw1_w[ch * 49 + t]); }
}

// ---------------------------------------------------------------------------
// Offset conv as MFMA implicit GEMM (fp16), full-row tile (128 pixels/block).
// (R10 structure: wave owns NT/4 oc-tiles x all 128 px.)
// ---------------------------------------------------------------------------
template<int K, int PAD, int DIL, int OCP, int KR>
__global__ __launch_bounds__(256, 4) void conv_mfma(
    const ushort* __restrict__ xp,
    const ushort* __restrict__ wp,
    const float* __restrict__ bias,
    ushort* __restrict__ outp) {
    constexpr int WIDTH = 128 + (K - 1) * DIL;
    constexpr int S = 2 * K * K;
    constexpr int SP = S + 2;
    constexpr int NT = OCP / 16;
    constexpr int TPW = (NT + 3) / 4;
    constexpr int STG = KR * WIDTH * 64;
    constexpr int EPI = 128 * SP;
    constexpr int LN = STG > EPI ? STG : EPI;
    __shared__ __align__(16) ushort lds[LN];

    const int bx = blockIdx.x;
    const int b = bx >> 7, h = bx & 127;
    const int tid = threadIdx.x, lane = tid & 63, wid = tid >> 6;
    const int l15 = lane & 15, lg = lane >> 4;

    f32x4 acc[TPW][8] = {};

    const int nph = (K + KR - 1) / KR;
    for (int ph = 0; ph < nph; ++ph) {
        const int kr0 = ph * KR;
        const int krn = (K - kr0 < KR) ? (K - kr0) : KR;
        __syncthreads();
        const int chunks = krn * WIDTH * 8;
        for (int q = tid; q < chunks; q += 256) {
            const int ki = q / (WIDTH * 8);
            const int r2 = q - ki * (WIDTH * 8);
            const int widx = r2 >> 3, csl = r2 & 7;
            const int y = h - PAD + (kr0 + ki) * DIL;
            const int w = -PAD + widx;
            uint4 v = make_uint4(0, 0, 0, 0);
            if ((unsigned)y < 128u && (unsigned)w < 128u)
                v = *(const uint4*)(xp + (((size_t)(b * 128 + y) * 128 + w) << 6) + (csl << 3));
            ((uint4*)lds)[(ki * WIDTH + widx) * 8 + (csl ^ (widx & 7))] = v;
        }
        __syncthreads();

        const int t1 = (kr0 + krn) * K;
        for (int t = kr0 * K; t < t1; ++t) {
            const int ki = t / K - kr0;
            const int kj = t - (t / K) * K;
            const int s0 = 2 * t;
            b16x8 a[2][TPW];
            #pragma unroll
            for (int i = 0; i < TPW; ++i) {
                if (wid + 4 * i < NT) {
                    const int ot = wid + 4 * i;
                    const size_t ab = ((size_t)(ot * 16 + l15)) * 32 + lg * 8;
                    a[0][i] = *(const b16x8*)(wp + (size_t)s0 * (OCP * 32) + ab);
                    a[1][i] = *(const b16x8*)(wp + (size_t)(s0 + 1) * (OCP * 32) + ab);
                }
            }
            const int wb0 = l15 + kj * DIL;
            int idx = (ki * WIDTH + wb0) * 8 + (lg ^ (wb0 & 7));
            #pragma unroll
            for (int pt = 0; pt < 8; ++pt) {
                const b16x8 b0 = ((const b16x8*)lds)[idx];
                const b16x8 b1 = ((const b16x8*)lds)[idx ^ 4];
                #pragma unroll
                for (int i = 0; i < TPW; ++i) {
                    if (wid + 4 * i < NT) {
                        acc[i][pt] = __builtin_amdgcn_mfma_f32_16x16x32_f16(s2h8(a[0][i]), s2h8(b0), acc[i][pt], 0, 0, 0);
                        acc[i][pt] = __builtin_amdgcn_mfma_f32_16x16x32_f16(s2h8(a[1][i]), s2h8(b1), acc[i][pt], 0, 0, 0);
                    }
                }
                idx += 128;
            }
        }
    }

    // Epilogue: acc -> LDS [128 pix][SP], then flat coalesced copy (S cols).
    __syncthreads();
    #pragma unroll
    for (int i = 0; i < TPW; ++i) {
        const int ot = wid + 4 * i;
        if (ot >= NT) continue;
        #pragma unroll
        for (int r = 0; r < 4; ++r) {
            const int oc = ot * 16 + lg * 4 + r;
            if (oc < S) {
                const float bv = bias[oc];
                #pragma unroll
                for (int pt = 0; pt < 8; ++pt)
                    lds[(pt * 16 + l15) * SP + oc] = f2h(acc[i][pt][r] + bv);
            }
        }
    }
    __syncthreads();
    constexpr int SH = S / 2, SPH = SP / 2;
    const uint* lu = (const uint*)lds;
    uint* og = (uint*)outp + ((size_t)bx << 7) * SH;
    for (int q = tid; q < 128 * SH; q += 256) {
        const int pix = q / SH, s = q - pix * SH;
        og[q] = lu[pix * SPH + s];
    }
}

// ---------------------------------------------------------------------------
// Deformable depthwise conv, NHWC fp16. 512-thread block, 64 pixels,
// NO tap split: all 8 waves walk taps in the SAME order (lockstep) so the
// per-ki-row 2-row window (~22KB/block) can be captured by L1; XCD swizzle
// keeps each image on one XCD's L2. Compact state: sIdx (4B) + sW (8B).
// ---------------------------------------------------------------------------
template <int K, int PAD, int DIL>
__global__ __launch_bounds__(512) void deform7k(
    const ushort* __restrict__ xp,   // [B*HW][64] fp16
    const ushort* __restrict__ off,  // [B*HW][2KK] fp16
    const ushort* __restrict__ dwt,  // [KK][64] fp16
    ushort* __restrict__ outb) {     // [B*HW][64] fp16
    constexpr int KK = K * K;
    __shared__ uint sIdx[64 * KK];
    __shared__ __align__(8) uint2 sW[64 * KK];
    __shared__ ushort dwl[KK * 64];
    const int tid = threadIdx.x;
    const int img = blockIdx.x & 7;              // XCD-locality swizzle
    const int pix0 = img * HW + (blockIdx.x >> 3) * 64;

    for (int i = tid; i < KK * 32; i += 512)
        ((uint*)dwl)[i] = ((const uint*)dwt)[i];

    // --- setup phase: 64*KK tasks over 512 threads ---
    const uint* og = (const uint*)off + (size_t)pix0 * KK;
    for (int q = tid; q < 64 * KK; q += 512) {
        const int pl2 = q / KK, t2 = q - pl2 * KK;
        const int pix = pix0 + pl2;
        const int h = (pix >> 7) & 127, w = pix & 127;
        const uint od = og[q];
        const int ki = t2 / K, kj = t2 - ki * K;
        const float py = (float)(h - PAD + ki * DIL) + h2f_lo(od);
        const float px = (float)(w - PAD + kj * DIL) + h2f_hi(od);
        const float y0f = floorf(py), x0f = floorf(px);
        const float wy = py - y0f, wx = px - x0f;
        const int y0 = (int)y0f, x0 = (int)x0f;
        const int y1 = y0 + 1, x1 = x0 + 1;
        const float m00 = ((unsigned)y0 < 128u && (unsigned)x0 < 128u) ? 1.f : 0.f;
        const float m01 = ((unsigned)y0 < 128u && (unsigned)x1 < 128u) ? 1.f : 0.f;
        const float m10 = ((unsigned)y1 < 128u && (unsigned)x0 < 128u) ? 1.f : 0.f;
        const float m11 = ((unsigned)y1 < 128u && (unsigned)x1 < 128u) ? 1.f : 0.f;
        const int y0c = min(max(y0, 0), 127), y1c = min(max(y1, 0), 127);
        const int x0c = min(max(x0, 0), 127), x1c = min(max(x1, 0), 127);
        const float w00 = (1.f - wy) * (1.f - wx) * m00;
        const float w01 = (1.f - wy) * wx * m01;
        const float w10 = wy * (1.f - wx) * m10;
        const float w11 = wy * wx * m11;
        const int i00 = (y0c << 7) | x0c;
        const int i11 = (y1c << 7) | x1c;
        const int dx = x1c - x0c;                      // 0 or 1
        sIdx[q] = (uint)i00 | ((uint)i11 << 14) | ((uint)dx << 28);
        sW[q] = make_uint2(pkrtz_u(w00, w01), pkrtz_u(w10, w11));
    }
    __syncthreads();

    // --- main phase: thread = (pixel pl in [0,64), 8-ch group g) ---
    const int g = tid & 7, pl = tid >> 3;
    const int pix = pix0 + pl;
    const int gb2 = g << 4;            // byte offset of channel group
    const char* xb8 = (const char*)xp + ((size_t)img << 21);
    const int base = pl * KK;

    __half2 acc_h[4] = {};

    #pragma unroll 2
    for (int tt = 0; tt < KK; ++tt) {
        const uint id = sIdx[base + tt];
        const uint2 w4 = sW[base + tt];
        const uint o00 = ((id & 16383u) << 7) + gb2;
        const uint o11 = (((id >> 14) & 16383u) << 7) + gb2;
        const uint dxb = (id >> 21) & 128u;
        const __half2 wv0 = u2hh(w4.x), wv1 = u2hh(w4.y);
        const __half2 w00b = __low2half2(wv0), w01b = __high2half2(wv0);
        const __half2 w10b = __low2half2(wv1), w11b = __high2half2(wv1);
        const uint4 qa = *(const uint4*)(xb8 + o00);
        const uint4 qb = *(const uint4*)(xb8 + (o00 + dxb));
        const uint4 qc = *(const uint4*)(xb8 + (o11 - dxb));
        const uint4 qd = *(const uint4*)(xb8 + o11);
        const uint4 dwv = *(const uint4*)(dwl + (tt << 6) + (g << 3));
        const uint* Ap = (const uint*)&qa;
        const uint* Bp = (const uint*)&qb;
        const uint* Cp = (const uint*)&qc;
        const uint* Dp = (const uint*)&qd;
        const uint* Wp = (const uint*)&dwv;
        #pragma unroll
        for (int j = 0; j < 4; ++j) {
            __half2 v = __hmul2(u2hh(Ap[j]), w00b);
            v = __hfma2(u2hh(Bp[j]), w01b, v);
            v = __hfma2(u2hh(Cp[j]), w10b, v);
            v = __hfma2(u2hh(Dp[j]), w11b, v);
            acc_h[j] = __hfma2(v, u2hh(Wp[j]), acc_h[j]);
        }
    }

    uint o4[4];
    #pragma unroll
    for (int j = 0; j < 4; ++j) o4[j] = hh2u(acc_h[j]);
    *(uint4*)(outb + ((size_t)pix << 6) + (g << 3)) = *(uint4*)o4;
}

// ---------------------------------------------------------------------------
// Fused 1x1 conv (fp16 MFMA) + bias + u*attn. attn NHWC fp16; x/out NCHW f32.
// ---------------------------------------------------------------------------
__global__ __launch_bounds__(256) void pw_mfma(
    const ushort* __restrict__ attn, const ushort* __restrict__ wp2,
    const float* __restrict__ b1, const float* __restrict__ x,
    float* __restrict__ out) {
    __shared__ __align__(16) ushort lds[64 * 64];
    const int tid = threadIdx.x, lane = tid & 63, wid = tid >> 6;
    const int l15 = lane & 15, lg = lane >> 4;
    const int pix0 = blockIdx.x << 6;

    const uint4* src = (const uint4*)(attn + ((size_t)pix0 << 6));
    for (int q = tid; q < 512; q += 256) {
        const int widx = q >> 3, csl = q & 7;
        ((uint4*)lds)[widx * 8 + (csl ^ (widx & 7))] = src[q];
    }
    __syncthreads();

    const b16x8 a0 = *(const b16x8*)(wp2 + ((size_t)(wid * 16 + l15)) * 32 + lg * 8);
    const b16x8 a1 = *(const b16x8*)(wp2 + ((size_t)(64 + wid * 16 + l15)) * 32 + lg * 8);
    f32x4 acc[4] = {};
    #pragma unroll
    for (int pt = 0; pt < 4; ++pt) {
        const int wb = pt * 16 + l15;
        const int idx = wb * 8 + (lg ^ (wb & 7));
        const b16x8 b0 = ((const b16x8*)lds)[idx];
        const b16x8 b1v = ((const b16x8*)lds)[idx ^ 4];
        acc[pt] = __builtin_amdgcn_mfma_f32_16x16x32_f16(s2h8(a0), s2h8(b0), acc[pt], 0, 0, 0);
        acc[pt] = __builtin_amdgcn_mfma_f32_16x16x32_f16(s2h8(a1), s2h8(b1v), acc[pt], 0, 0, 0);
    }

    const int b = pix0 >> 14, hw0 = pix0 & 16383;
    #pragma unroll
    for (int r = 0; r < 4; ++r) {
        const int oc = wid * 16 + lg * 4 + r;
        const float bv = b1[oc];
        const size_t base = (((size_t)b * 64 + oc) << 14) + hw0;
        #pragma unroll
        for (int pt = 0; pt < 4; ++pt) {
            const size_t oi = base + pt * 16 + l15;
            out[oi] = x[oi] * (acc[pt][r] + bv);
        }
    }
}

extern "C" void kernel_launch(void* const* d_in, const int* in_sizes, int n_in,
                              void* d_out, int out_size, void* d_ws, size_t ws_size,
                              hipStream_t stream) {
    const float* x       = (const float*)d_in[0];
    const float* off0_w  = (const float*)d_in[1];
    const float* off0_b  = (const float*)d_in[2];
    const float* dw0_w   = (const float*)d_in[3];
    const float* off1_w  = (const float*)d_in[4];
    const float* off1_b  = (const float*)d_in[5];
    const float* dw1_w   = (const float*)d_in[6];
    const float* conv1_w = (const float*)d_in[7];
    const float* conv1_b = (const float*)d_in[8];
    float* out = (float*)d_out;

    const size_t NPX = (size_t)Bb * HW;
    ushort* xp     = (ushort*)d_ws;
    ushort* attn0b = xp + NPX * 64;
    ushort* attn1b = attn0b + NPX * 64;
    ushort* offb   = attn1b + NPX * 64;
    ushort* wp0    = offb + NPX * 98;
    ushort* wp1    = wp0 + 50 * 64 * 32;
    ushort* wpP    = wp1 + 98 * 112 * 32;
    ushort* dwt0   = wpP + 2 * 64 * 32;
    ushort* dwt1   = dwt0 + 25 * 64;

    const dim3 blk(256);

    pack_nhwc<<<2048, blk, 0, stream>>>(x, xp);
    // fused small packs: 102400+351232+4096+1600+3136 = 462464 elements
    pack_all<<<(462464 + 255) / 256, blk, 0, stream>>>(
        off0_w, wp0, off1_w, wp1, conv1_w, wpP, dw0_w, dwt0, dw1_w, dwt1);

    // Stage 1
    conv_mfma<5, 2, 1, 64, 2><<<1024, blk, 0, stream>>>(xp, wp0, off0_b, offb);
    deform7k<5, 2, 1><<<2048, 512, 0, stream>>>(xp, offb, dwt0, attn0b);

    // Stage 2
    conv_mfma<7, 9, 3, 112, 2><<<1024, blk, 0, stream>>>(attn0b, wp1, off1_b, offb);
    deform7k<7, 9, 3><<<2048, 512, 0, stream>>>(attn0b, offb, dwt1, attn1b);

    // Stage 3
    pw_mfma<<<2048, blk, 0, stream>>>(attn1b, wpP, conv1_b, x, out);
}

// Round 16
// 296.772 us; speedup vs baseline: 1.0698x; 1.0182x over previous
//
#include <hip/hip_runtime.h>
#include <hip/hip_fp16.h>

#define Bb 8
#define C  64
#define Hh 128
#define Ww 128
#define HW (Hh * Ww)

typedef __attribute__((ext_vector_type(8))) short b16x8;   // raw 16B block
typedef __attribute__((ext_vector_type(4))) float f32x4;
typedef _Float16 f16x8 __attribute__((ext_vector_type(8)));
typedef __fp16 fp16x2cv __attribute__((ext_vector_type(2)));  // cvt_pkrtz ret

__device__ __forceinline__ ushort f2h(float f) {
    union { _Float16 h; ushort u; } z; z.h = (_Float16)f; return z.u;
}
__device__ __forceinline__ uint pkrtz_u(float a, float b) {
    union { fp16x2cv h; uint u; } z;
    z.h = __builtin_amdgcn_cvt_pkrtz(a, b); return z.u;
}
__device__ __forceinline__ f16x8 s2h8(b16x8 s) {
    union { b16x8 s; f16x8 h; } x; x.s = s; return x.h;
}
__device__ __forceinline__ __half2 u2hh(uint u) {
    union { uint u; __half2 h; } x; x.u = u; return x.h;
}
__device__ __forceinline__ uint hh2u(__half2 h) {
    union { uint u; __half2 h; } x; x.h = h; return x.u;
}
__device__ __forceinline__ float h2f_lo(uint u) {
    union { uint u; __half2 h; } x; x.u = u; return __low2float(x.h);
}
__device__ __forceinline__ float h2f_hi(uint u) {
    union { uint u; __half2 h; } x; x.u = u; return __high2float(x.h);
}

// ---------------------------------------------------------------------------
// NCHW fp32 -> NHWC fp16 (c innermost), transposed through LDS.
// ---------------------------------------------------------------------------
__global__ void pack_nhwc(const float* __restrict__ in, ushort* __restrict__ out) {
    __shared__ ushort t[64][65];
    const int bx = blockIdx.x;
    const int b = bx >> 8, rem = bx & 255, h = rem >> 1, w0 = (rem & 1) << 6;
    const int x = threadIdx.x, wl = x & 63, cs = x >> 6;
    const float* ip = in + (((size_t)b * 64) << 14) + (h << 7) + w0 + wl;
    #pragma unroll
    for (int i = 0; i < 16; ++i) {
        const int c = i * 4 + cs;
        t[wl][c] = f2h(ip[(size_t)c << 14]);
    }
    __syncthreads();
    ushort* op = out + ((size_t)((b * Hh + h) * Ww + w0)) * 64 + wl;
    #pragma unroll
    for (int i = 0; i < 16; ++i) {
        const int w = i * 4 + cs;
        op[(size_t)w * 64] = t[w][wl];
    }
}

// ---------------------------------------------------------------------------
// ONE fused weight-pack kernel (5 jobs): 3x pack_w + 2x pack_dwt.
// ---------------------------------------------------------------------------
__device__ __forceinline__ void do_pack_w(const float* src, ushort* dst,
                                          int OC, int OCP, int KK, int idx) {
    const int kk = idx & 31;
    const int oc = (idx >> 5) % OCP;
    const int s = idx / (32 * OCP);
    const int c = (s & 1) * 32 + kk;
    const int t = s >> 1;
    const float v = (oc < OC) ? src[((size_t)oc * 64 + c) * KK + t] : 0.f;
    dst[idx] = f2h(v);
}
__global__ void pack_all(const float* __restrict__ off0_w, ushort* __restrict__ wp0,
                         const float* __restrict__ off1_w, ushort* __restrict__ wp1,
                         const float* __restrict__ conv1_w, ushort* __restrict__ wpP,
                         const float* __restrict__ dw0_w, ushort* __restrict__ dwt0,
                         const float* __restrict__ dw1_w, ushort* __restrict__ dwt1) {
    const int n0 = 2 * 25 * 64 * 32;       // 102400
    const int n1 = 2 * 49 * 112 * 32;      // 351232
    const int n2 = 2 * 64 * 32;            // 4096
    const int n3 = 25 * 64;                // 1600
    const int n4 = 49 * 64;                // 3136
    int idx = blockIdx.x * 256 + threadIdx.x;
    if (idx < n0) { do_pack_w(off0_w, wp0, 50, 64, 25, idx); return; }
    idx -= n0;
    if (idx < n1) { do_pack_w(off1_w, wp1, 98, 112, 49, idx); return; }
    idx -= n1;
    if (idx < n2) { do_pack_w(conv1_w, wpP, 64, 64, 1, idx); return; }
    idx -= n2;
    if (idx < n3) { const int t = idx >> 6, ch = idx & 63;
                    dwt0[idx] = f2h(dw0_w[ch * 25 + t]); return; }
    idx -= n3;
    if (idx < n4) { const int t = idx >> 6, ch = idx & 63;
                    dwt1[idx] = f2h(dw1_w[ch * 49 + t]); }
}

// ---------------------------------------------------------------------------
// Offset conv as MFMA implicit GEMM (fp16), full-row tile (128 pixels/block).
// XCD swizzle: b = bx & 7 -> all rows of one image (and its K-row reuse +
// weight panel) stay in one XCD's L2.
// ---------------------------------------------------------------------------
template<int K, int PAD, int DIL, int OCP, int KR>
__global__ __launch_bounds__(256, 4) void conv_mfma(
    const ushort* __restrict__ xp,
    const ushort* __restrict__ wp,
    const float* __restrict__ bias,
    ushort* __restrict__ outp) {
    constexpr int WIDTH = 128 + (K - 1) * DIL;
    constexpr int S = 2 * K * K;
    constexpr int SP = S + 2;
    constexpr int NT = OCP / 16;
    constexpr int TPW = (NT + 3) / 4;
    constexpr int STG = KR * WIDTH * 64;
    constexpr int EPI = 128 * SP;
    constexpr int LN = STG > EPI ? STG : EPI;
    __shared__ __align__(16) ushort lds[LN];

    const int bx = blockIdx.x;
    const int b = bx & 7, h = bx >> 3;          // XCD-locality swizzle
    const int tid = threadIdx.x, lane = tid & 63, wid = tid >> 6;
    const int l15 = lane & 15, lg = lane >> 4;

    f32x4 acc[TPW][8] = {};

    const int nph = (K + KR - 1) / KR;
    for (int ph = 0; ph < nph; ++ph) {
        const int kr0 = ph * KR;
        const int krn = (K - kr0 < KR) ? (K - kr0) : KR;
        __syncthreads();
        const int chunks = krn * WIDTH * 8;
        for (int q = tid; q < chunks; q += 256) {
            const int ki = q / (WIDTH * 8);
            const int r2 = q - ki * (WIDTH * 8);
            const int widx = r2 >> 3, csl = r2 & 7;
            const int y = h - PAD + (kr0 + ki) * DIL;
            const int w = -PAD + widx;
            uint4 v = make_uint4(0, 0, 0, 0);
            if ((unsigned)y < 128u && (unsigned)w < 128u)
                v = *(const uint4*)(xp + (((size_t)(b * 128 + y) * 128 + w) << 6) + (csl << 3));
            ((uint4*)lds)[(ki * WIDTH + widx) * 8 + (csl ^ (widx & 7))] = v;
        }
        __syncthreads();

        const int t1 = (kr0 + krn) * K;
        for (int t = kr0 * K; t < t1; ++t) {
            const int ki = t / K - kr0;
            const int kj = t - (t / K) * K;
            const int s0 = 2 * t;
            b16x8 a[2][TPW];
            #pragma unroll
            for (int i = 0; i < TPW; ++i) {
                if (wid + 4 * i < NT) {
                    const int ot = wid + 4 * i;
                    const size_t ab = ((size_t)(ot * 16 + l15)) * 32 + lg * 8;
                    a[0][i] = *(const b16x8*)(wp + (size_t)s0 * (OCP * 32) + ab);
                    a[1][i] = *(const b16x8*)(wp + (size_t)(s0 + 1) * (OCP * 32) + ab);
                }
            }
            const int wb0 = l15 + kj * DIL;
            int idx = (ki * WIDTH + wb0) * 8 + (lg ^ (wb0 & 7));
            #pragma unroll
            for (int pt = 0; pt < 8; ++pt) {
                const b16x8 b0 = ((const b16x8*)lds)[idx];
                const b16x8 b1 = ((const b16x8*)lds)[idx ^ 4];
                #pragma unroll
                for (int i = 0; i < TPW; ++i) {
                    if (wid + 4 * i < NT) {
                        acc[i][pt] = __builtin_amdgcn_mfma_f32_16x16x32_f16(s2h8(a[0][i]), s2h8(b0), acc[i][pt], 0, 0, 0);
                        acc[i][pt] = __builtin_amdgcn_mfma_f32_16x16x32_f16(s2h8(a[1][i]), s2h8(b1), acc[i][pt], 0, 0, 0);
                    }
                }
                idx += 128;
            }
        }
    }

    __syncthreads();
    #pragma unroll
    for (int i = 0; i < TPW; ++i) {
        const int ot = wid + 4 * i;
        if (ot >= NT) continue;
        #pragma unroll
        for (int r = 0; r < 4; ++r) {
            const int oc = ot * 16 + lg * 4 + r;
            if (oc < S) {
                const float bv = bias[oc];
                #pragma unroll
                for (int pt = 0; pt < 8; ++pt)
                    lds[(pt * 16 + l15) * SP + oc] = f2h(acc[i][pt][r] + bv);
            }
        }
    }
    __syncthreads();
    constexpr int SH = S / 2, SPH = SP / 2;
    const uint* lu = (const uint*)lds;
    uint* og = (uint*)outp + ((size_t)(b * 128 + h) << 7) * SH;
    for (int q = tid; q < 128 * SH; q += 256) {
        const int pix = q / SH, s = q - pix * SH;
        og[q] = lu[pix * SPH + s];
    }
}

// ---------------------------------------------------------------------------
// Deformable depthwise conv, NHWC fp16. 512-thread block, 64 pixels,
// lockstep taps, XCD swizzle (img = blockIdx & 7). At the L2-BW wall
// (~87% of 34.5 TB/s on corner gathers) — verified across 5 variants.
// ---------------------------------------------------------------------------
template <int K, int PAD, int DIL>
__global__ __launch_bounds__(512) void deform7k(
    const ushort* __restrict__ xp,   // [B*HW][64] fp16
    const ushort* __restrict__ off,  // [B*HW][2KK] fp16
    const ushort* __restrict__ dwt,  // [KK][64] fp16
    ushort* __restrict__ outb) {     // [B*HW][64] fp16
    constexpr int KK = K * K;
    __shared__ uint sIdx[64 * KK];
    __shared__ __align__(8) uint2 sW[64 * KK];
    __shared__ ushort dwl[KK * 64];
    const int tid = threadIdx.x;
    const int img = blockIdx.x & 7;              // XCD-locality swizzle
    const int pix0 = img * HW + (blockIdx.x >> 3) * 64;

    for (int i = tid; i < KK * 32; i += 512)
        ((uint*)dwl)[i] = ((const uint*)dwt)[i];

    const uint* og = (const uint*)off + (size_t)pix0 * KK;
    for (int q = tid; q < 64 * KK; q += 512) {
        const int pl2 = q / KK, t2 = q - pl2 * KK;
        const int pix = pix0 + pl2;
        const int h = (pix >> 7) & 127, w = pix & 127;
        const uint od = og[q];
        const int ki = t2 / K, kj = t2 - ki * K;
        const float py = (float)(h - PAD + ki * DIL) + h2f_lo(od);
        const float px = (float)(w - PAD + kj * DIL) + h2f_hi(od);
        const float y0f = floorf(py), x0f = floorf(px);
        const float wy = py - y0f, wx = px - x0f;
        const int y0 = (int)y0f, x0 = (int)x0f;
        const int y1 = y0 + 1, x1 = x0 + 1;
        const float m00 = ((unsigned)y0 < 128u && (unsigned)x0 < 128u) ? 1.f : 0.f;
        const float m01 = ((unsigned)y0 < 128u && (unsigned)x1 < 128u) ? 1.f : 0.f;
        const float m10 = ((unsigned)y1 < 128u && (unsigned)x0 < 128u) ? 1.f : 0.f;
        const float m11 = ((unsigned)y1 < 128u && (unsigned)x1 < 128u) ? 1.f : 0.f;
        const int y0c = min(max(y0, 0), 127), y1c = min(max(y1, 0), 127);
        const int x0c = min(max(x0, 0), 127), x1c = min(max(x1, 0), 127);
        const float w00 = (1.f - wy) * (1.f - wx) * m00;
        const float w01 = (1.f - wy) * wx * m01;
        const float w10 = wy * (1.f - wx) * m10;
        const float w11 = wy * wx * m11;
        const int i00 = (y0c << 7) | x0c;
        const int i11 = (y1c << 7) | x1c;
        const int dx = x1c - x0c;
        sIdx[q] = (uint)i00 | ((uint)i11 << 14) | ((uint)dx << 28);
        sW[q] = make_uint2(pkrtz_u(w00, w01), pkrtz_u(w10, w11));
    }
    __syncthreads();

    const int g = tid & 7, pl = tid >> 3;
    const int pix = pix0 + pl;
    const int gb2 = g << 4;
    const char* xb8 = (const char*)xp + ((size_t)img << 21);
    const int base = pl * KK;

    __half2 acc_h[4] = {};

    #pragma unroll 2
    for (int tt = 0; tt < KK; ++tt) {
        const uint id = sIdx[base + tt];
        const uint2 w4 = sW[base + tt];
        const uint o00 = ((id & 16383u) << 7) + gb2;
        const uint o11 = (((id >> 14) & 16383u) << 7) + gb2;
        const uint dxb = (id >> 21) & 128u;
        const __half2 wv0 = u2hh(w4.x), wv1 = u2hh(w4.y);
        const __half2 w00b = __low2half2(wv0), w01b = __high2half2(wv0);
        const __half2 w10b = __low2half2(wv1), w11b = __high2half2(wv1);
        const uint4 qa = *(const uint4*)(xb8 + o00);
        const uint4 qb = *(const uint4*)(xb8 + (o00 + dxb));
        const uint4 qc = *(const uint4*)(xb8 + (o11 - dxb));
        const uint4 qd = *(const uint4*)(xb8 + o11);
        const uint4 dwv = *(const uint4*)(dwl + (tt << 6) + (g << 3));
        const uint* Ap = (const uint*)&qa;
        const uint* Bp = (const uint*)&qb;
        const uint* Cp = (const uint*)&qc;
        const uint* Dp = (const uint*)&qd;
        const uint* Wp = (const uint*)&dwv;
        #pragma unroll
        for (int j = 0; j < 4; ++j) {
            __half2 v = __hmul2(u2hh(Ap[j]), w00b);
            v = __hfma2(u2hh(Bp[j]), w01b, v);
            v = __hfma2(u2hh(Cp[j]), w10b, v);
            v = __hfma2(u2hh(Dp[j]), w11b, v);
            acc_h[j] = __hfma2(v, u2hh(Wp[j]), acc_h[j]);
        }
    }

    uint o4[4];
    #pragma unroll
    for (int j = 0; j < 4; ++j) o4[j] = hh2u(acc_h[j]);
    *(uint4*)(outb + ((size_t)pix << 6) + (g << 3)) = *(uint4*)o4;
}

// ---------------------------------------------------------------------------
// Fused 1x1 conv (fp16 MFMA) + bias + u*attn. attn NHWC fp16; x/out NCHW f32.
// ---------------------------------------------------------------------------
__global__ __launch_bounds__(256) void pw_mfma(
    const ushort* __restrict__ attn, const ushort* __restrict__ wp2,
    const float* __restrict__ b1, const float* __restrict__ x,
    float* __restrict__ out) {
    __shared__ __align__(16) ushort lds[64 * 64];
    const int tid = threadIdx.x, lane = tid & 63, wid = tid >> 6;
    const int l15 = lane & 15, lg = lane >> 4;
    const int pix0 = blockIdx.x << 6;

    const uint4* src = (const uint4*)(attn + ((size_t)pix0 << 6));
    for (int q = tid; q < 512; q += 256) {
        const int widx = q >> 3, csl = q & 7;
        ((uint4*)lds)[widx * 8 + (csl ^ (widx & 7))] = src[q];
    }
    __syncthreads();

    const b16x8 a0 = *(const b16x8*)(wp2 + ((size_t)(wid * 16 + l15)) * 32 + lg * 8);
    const b16x8 a1 = *(const b16x8*)(wp2 + ((size_t)(64 + wid * 16 + l15)) * 32 + lg * 8);
    f32x4 acc[4] = {};
    #pragma unroll
    for (int pt = 0; pt < 4; ++pt) {
        const int wb = pt * 16 + l15;
        const int idx = wb * 8 + (lg ^ (wb & 7));
        const b16x8 b0 = ((const b16x8*)lds)[idx];
        const b16x8 b1v = ((const b16x8*)lds)[idx ^ 4];
        acc[pt] = __builtin_amdgcn_mfma_f32_16x16x32_f16(s2h8(a0), s2h8(b0), acc[pt], 0, 0, 0);
        acc[pt] = __builtin_amdgcn_mfma_f32_16x16x32_f16(s2h8(a1), s2h8(b1v), acc[pt], 0, 0, 0);
    }

    const int b = pix0 >> 14, hw0 = pix0 & 16383;
    #pragma unroll
    for (int r = 0; r < 4; ++r) {
        const int oc = wid * 16 + lg * 4 + r;
        const float bv = b1[oc];
        const size_t base = (((size_t)b * 64 + oc) << 14) + hw0;
        #pragma unroll
        for (int pt = 0; pt < 4; ++pt) {
            const size_t oi = base + pt * 16 + l15;
            out[oi] = x[oi] * (acc[pt][r] + bv);
        }
    }
}

extern "C" void kernel_launch(void* const* d_in, const int* in_sizes, int n_in,
                              void* d_out, int out_size, void* d_ws, size_t ws_size,
                              hipStream_t stream) {
    const float* x       = (const float*)d_in[0];
    const float* off0_w  = (const float*)d_in[1];
    const float* off0_b  = (const float*)d_in[2];
    const float* dw0_w   = (const float*)d_in[3];
    const float* off1_w  = (const float*)d_in[4];
    const float* off1_b  = (const float*)d_in[5];
    const float* dw1_w   = (const float*)d_in[6];
    const float* conv1_w = (const float*)d_in[7];
    const float* conv1_b = (const float*)d_in[8];
    float* out = (float*)d_out;

    const size_t NPX = (size_t)Bb * HW;
    ushort* xp     = (ushort*)d_ws;
    ushort* attn0b = xp + NPX * 64;
    ushort* attn1b = attn0b + NPX * 64;
    ushort* offb   = attn1b + NPX * 64;
    ushort* wp0    = offb + NPX * 98;
    ushort* wp1    = wp0 + 50 * 64 * 32;
    ushort* wpP    = wp1 + 98 * 112 * 32;
    ushort* dwt0   = wpP + 2 * 64 * 32;
    ushort* dwt1   = dwt0 + 25 * 64;

    const dim3 blk(256);

    pack_nhwc<<<2048, blk, 0, stream>>>(x, xp);
    pack_all<<<(462464 + 255) / 256, blk, 0, stream>>>(
        off0_w, wp0, off1_w, wp1, conv1_w, wpP, dw0_w, dwt0, dw1_w, dwt1);

    // Stage 1
    conv_mfma<5, 2, 1, 64, 2><<<1024, blk, 0, stream>>>(xp, wp0, off0_b, offb);
    deform7k<5, 2, 1><<<2048, 512, 0, stream>>>(xp, offb, dwt0, attn0b);

    // Stage 2
    conv_mfma<7, 9, 3, 112, 2><<<1024, blk, 0, stream>>>(attn0b, wp1, off1_b, offb);
    deform7k<7, 9, 3><<<2048, 512, 0, stream>>>(attn0b, offb, dwt1, attn1b);

    // Stage 3
    pw_mfma<<<2048, blk, 0, stream>>>(attn1b, wpP, conv1_b, x, out);
}